// Round 1
// baseline (270.149 us; speedup 1.0000x reference)
//
#include <hip/hip_runtime.h>
#include <hip/hip_bf16.h>
#include <cstdint>

// Problem constants
#define B_ 4
#define S_ 4096
#define D_ 512
#define M_ (B_*S_)   // 16384 rows for the [M,D] GEMMs

typedef __bf16 bf16;
typedef __bf16 bf16x8 __attribute__((ext_vector_type(8)));
typedef float  f32x4  __attribute__((ext_vector_type(4)));

typedef __attribute__((address_space(1))) void* as1p;
typedef __attribute__((address_space(3))) void* as3p;

__device__ __forceinline__ void gl2lds16(const void* g, void* l) {
    // async global->LDS, 16B per lane; LDS dest = wave-uniform base + lane*16
    __builtin_amdgcn_global_load_lds((as1p)g, (as3p)l, 16, 0, 0);
}

// ---------------- prep: fp32 -> bf16 casts + zero Z ----------------
__global__ __launch_bounds__(256) void prep_kernel(
    const float* __restrict__ xs,
    const float* __restrict__ Wk, const float* __restrict__ Wq,
    const float* __restrict__ Wv, const float* __restrict__ Wl,
    bf16* __restrict__ xs_b, bf16* __restrict__ Wk_b, bf16* __restrict__ Wq_b,
    bf16* __restrict__ Wv_b, bf16* __restrict__ Wl_b, float* __restrict__ Z)
{
    const int XS_CHUNKS = M_*D_/8;       // 2,097,152 chunks of 8 floats
    const int W_CHUNKS  = D_*D_/8;       // 32,768 per weight
    int tid = blockIdx.x*256 + threadIdx.x;
    if (tid < XS_CHUNKS) {
        const float4* s4 = (const float4*)xs + (size_t)tid*2;
        float4 a = s4[0], b = s4[1];
        bf16x8 o;
        o[0]=(bf16)a.x; o[1]=(bf16)a.y; o[2]=(bf16)a.z; o[3]=(bf16)a.w;
        o[4]=(bf16)b.x; o[5]=(bf16)b.y; o[6]=(bf16)b.z; o[7]=(bf16)b.w;
        *((bf16x8*)xs_b + tid) = o;
    } else if (tid < XS_CHUNKS + 4*W_CHUNKS) {
        int w = tid - XS_CHUNKS;
        int which = w / W_CHUNKS, off = w % W_CHUNKS;
        const float* src; bf16* dst;
        switch (which) {
            case 0:  src = Wk; dst = Wk_b; break;
            case 1:  src = Wq; dst = Wq_b; break;
            case 2:  src = Wv; dst = Wv_b; break;
            default: src = Wl; dst = Wl_b; break;
        }
        const float4* s4 = (const float4*)src + (size_t)off*2;
        float4 a = s4[0], b = s4[1];
        bf16x8 o;
        o[0]=(bf16)a.x; o[1]=(bf16)a.y; o[2]=(bf16)a.z; o[3]=(bf16)a.w;
        o[4]=(bf16)b.x; o[5]=(bf16)b.y; o[6]=(bf16)b.z; o[7]=(bf16)b.w;
        *((bf16x8*)dst + off) = o;
    } else if (tid < XS_CHUNKS + 4*W_CHUNKS + M_/4) {
        int z = tid - (XS_CHUNKS + 4*W_CHUNKS);
        ((float4*)Z)[z] = make_float4(0.f, 0.f, 0.f, 0.f);
    }
}

// ---------------- generic 128x128 bf16 gemm_bt (C = A @ B^T), K = 512 ----------------
// ASTAGE: 0 = global_load_lds A directly; 1 = A := rowsum[row] * A (V), via regs->LDS
// EPI:    0 = bf16 store of (acc + bias[n])          (QKV; grid.z selects weight/bias/out)
//         1 = E = exp(acc/512) bf16 store + column-sum -> atomicAdd Z   (QK^T; grid.z = batch)
//         2 = f32 store of tanh(acc + bias[n])       (output GEMM)
template<int ASTAGE, int EPI>
__global__ __launch_bounds__(256, 2)
void gemm_bt(const bf16* __restrict__ A, const bf16* __restrict__ Bt,
             const float* __restrict__ b0, const float* __restrict__ b1, const float* __restrict__ b2,
             void* __restrict__ CoutV, float* __restrict__ Z, const float* __restrict__ rowsum,
             int ldc, long strideA, long strideB, long strideC, int strideZ)
{
    constexpr int K = 512;
    __shared__ bf16 lA[128*32];
    __shared__ bf16 lB[128*32];

    const int t    = threadIdx.x;
    const int bz   = blockIdx.z;
    const int m0   = blockIdx.x * 128;
    const int n0   = blockIdx.y * 128;
    const int lane = t & 63;
    const int wid  = t >> 6;
    const int wm   = (wid & 1) << 6;   // wave row origin in tile
    const int wn   = (wid >> 1) << 6;  // wave col origin in tile

    const char* Abase = (const char*)(A  + (long)bz * strideA);
    const char* Bbase = (const char*)(Bt + (long)bz * strideB);
    const float* bias = (bz == 0) ? b0 : ((bz == 1) ? b1 : b2);

    // staging: thread t covers tile-linear bytes [t*16,+16) and [4096+t*16,+16)
    const int srow = t >> 2;           // tile row for j=0 (0..63)
    const int skb  = (t & 3) << 4;     // byte offset within 64B row
    const long aoff0 = (long)(m0 + srow) * (K*2) + skb;
    const long aoff1 = aoff0 + (long)64 * (K*2);
    const long boff0 = (long)(n0 + srow) * (K*2) + skb;
    const long boff1 = boff0 + (long)64 * (K*2);
    char* ldsA = (char*)lA;
    char* ldsB = (char*)lB;
    const unsigned wbase = (unsigned)wid << 10;

    float rs0 = 0.f, rs1 = 0.f;
    if constexpr (ASTAGE == 1) {
        rs0 = rowsum[m0 + srow];
        rs1 = rowsum[m0 + srow + 64];
    }

    f32x4 acc[4][4] = {};

    const int ael = (wm + (lane & 15)) * 32 + ((lane >> 4) << 3);  // A frag base (elements)
    const int bel = (wn + (lane & 15)) * 32 + ((lane >> 4) << 3);  // B frag base

    for (int k0 = 0; k0 < K; k0 += 32) {
        __syncthreads();
        const long kb = (long)k0 * 2;
        if constexpr (ASTAGE == 0) {
            gl2lds16(Abase + aoff0 + kb, ldsA + wbase);
            gl2lds16(Abase + aoff1 + kb, ldsA + 4096 + wbase);
        } else {
            bf16x8 v0 = *(const bf16x8*)(Abase + aoff0 + kb);
            bf16x8 v1 = *(const bf16x8*)(Abase + aoff1 + kb);
            bf16x8 o0, o1;
            #pragma unroll
            for (int q = 0; q < 8; q++) {
                o0[q] = (bf16)((float)v0[q] * rs0);
                o1[q] = (bf16)((float)v1[q] * rs1);
            }
            *(bf16x8*)(ldsA + t*16)        = o0;
            *(bf16x8*)(ldsA + 4096 + t*16) = o1;
        }
        gl2lds16(Bbase + boff0 + kb, ldsB + wbase);
        gl2lds16(Bbase + boff1 + kb, ldsB + 4096 + wbase);
        __syncthreads();

        bf16x8 af[4], bfv[4];
        #pragma unroll
        for (int i = 0; i < 4; i++) af[i]  = *(const bf16x8*)(lA + ael + i*512);
        #pragma unroll
        for (int j = 0; j < 4; j++) bfv[j] = *(const bf16x8*)(lB + bel + j*512);
        #pragma unroll
        for (int i = 0; i < 4; i++)
            #pragma unroll
            for (int j = 0; j < 4; j++)
                acc[i][j] = __builtin_amdgcn_mfma_f32_16x16x32_bf16(af[i], bfv[j], acc[i][j], 0, 0, 0);
    }

    // epilogue: D[row][col], row = (lane>>4)*4 + reg (+16*i), col = lane&15 (+16*j)
    const int crb = m0 + wm + ((lane >> 4) << 2);
    const int ccb = n0 + wn + (lane & 15);

    if constexpr (EPI == 0) {
        bf16* C = (bf16*)CoutV + (long)bz * strideC;
        #pragma unroll
        for (int i = 0; i < 4; i++)
            #pragma unroll
            for (int j = 0; j < 4; j++) {
                float bj = bias[ccb + j*16];
                #pragma unroll
                for (int r = 0; r < 4; r++)
                    C[(long)(crb + i*16 + r) * ldc + ccb + j*16] = (bf16)(acc[i][j][r] + bj);
            }
    } else if constexpr (EPI == 1) {
        bf16* C = (bf16*)CoutV + (long)bz * strideC;
        float cs[4] = {0.f, 0.f, 0.f, 0.f};
        #pragma unroll
        for (int i = 0; i < 4; i++)
            #pragma unroll
            for (int j = 0; j < 4; j++)
                #pragma unroll
                for (int r = 0; r < 4; r++) {
                    float e = __expf(acc[i][j][r] * (1.0f/512.0f));
                    C[(long)(crb + i*16 + r) * ldc + ccb + j*16] = (bf16)e;
                    cs[j] += e;
                }
        #pragma unroll
        for (int j = 0; j < 4; j++) {
            float s = cs[j];
            s += __shfl_xor(s, 16);  // sum across quads (rows), same column
            s += __shfl_xor(s, 32);
            if (lane < 16) atomicAdd(&Z[bz * strideZ + n0 + wn + j*16 + lane], s);
        }
    } else {
        float* C = (float*)CoutV + (long)bz * strideC;
        #pragma unroll
        for (int i = 0; i < 4; i++)
            #pragma unroll
            for (int j = 0; j < 4; j++) {
                float bj = bias[ccb + j*16];
                #pragma unroll
                for (int r = 0; r < 4; r++) {
                    float x  = acc[i][j][r] + bj;
                    float e2 = __expf(2.0f * x);
                    C[(long)(crb + i*16 + r) * ldc + ccb + j*16] = 1.0f - 2.0f / (e2 + 1.0f);
                }
            }
    }
}

// ---------------- invZ ----------------
__global__ __launch_bounds__(256) void invz_kernel(const float* __restrict__ Z, float* __restrict__ invZ)
{
    int i = blockIdx.x*256 + threadIdx.x;
    if (i < B_*S_) invZ[i] = 1.0f / Z[i];
}

// ---------------- rowsum[b,s] = sum_e E[b,s,e] * invZ[b,e]  (one wave per row) ----------------
__global__ __launch_bounds__(256) void rowsum_kernel(const bf16* __restrict__ E,
                                                     const float* __restrict__ invZ,
                                                     float* __restrict__ rowsum)
{
    int row  = blockIdx.x*4 + (threadIdx.x >> 6);   // 16384 rows, 4 waves/block
    int lane = threadIdx.x & 63;
    int b    = row >> 12;
    const bf16*  Er = E    + (long)row * S_;
    const float* iz = invZ + (long)b   * S_;
    float acc = 0.f;
    #pragma unroll
    for (int it = 0; it < 8; it++) {
        int e = it*512 + lane*8;
        bf16x8 v  = *(const bf16x8*)(Er + e);
        float4 z0 = *(const float4*)(iz + e);
        float4 z1 = *(const float4*)(iz + e + 4);
        acc += (float)v[0]*z0.x + (float)v[1]*z0.y + (float)v[2]*z0.z + (float)v[3]*z0.w
             + (float)v[4]*z1.x + (float)v[5]*z1.y + (float)v[6]*z1.z + (float)v[7]*z1.w;
    }
    #pragma unroll
    for (int m = 1; m < 64; m <<= 1) acc += __shfl_xor(acc, m);
    if (lane == 0) rowsum[row] = acc;
}

extern "C" void kernel_launch(void* const* d_in, const int* in_sizes, int n_in,
                              void* d_out, int out_size, void* d_ws, size_t ws_size,
                              hipStream_t stream)
{
    const float* xs = (const float*)d_in[0];
    const float* Wk = (const float*)d_in[1];
    const float* bk = (const float*)d_in[2];
    const float* Wq = (const float*)d_in[3];
    const float* bq = (const float*)d_in[4];
    const float* Wv = (const float*)d_in[5];
    const float* bv = (const float*)d_in[6];
    const float* Wl = (const float*)d_in[7];
    const float* bl = (const float*)d_in[8];
    float* out = (float*)d_out;

    // workspace layout (194.2 MB total)
    char* w = (char*)d_ws;
    bf16* xs_b = (bf16*)w;  w += (size_t)M_*D_*2;     // 16 MB
    bf16* Kb   = (bf16*)w;  w += (size_t)M_*D_*2;     // Kb,Qb,Vb contiguous (stride 8388608 elems)
    bf16* Qb   = (bf16*)w;  w += (size_t)M_*D_*2;
    bf16* Vb   = (bf16*)w;  w += (size_t)M_*D_*2;
    bf16* Wk_b = (bf16*)w;  w += (size_t)D_*D_*2;     // Wk,Wq,Wv,Wl contiguous (stride 262144 elems)
    bf16* Wq_b = (bf16*)w;  w += (size_t)D_*D_*2;
    bf16* Wv_b = (bf16*)w;  w += (size_t)D_*D_*2;
    bf16* Wl_b = (bf16*)w;  w += (size_t)D_*D_*2;
    float* Z    = (float*)w; w += (size_t)M_*4;
    float* invZ = (float*)w; w += (size_t)M_*4;
    float* rs   = (float*)w; w += (size_t)M_*4;
    bf16* E    = (bf16*)w;  w += (size_t)B_*S_*S_*2;  // 134 MB
    if ((size_t)(w - (char*)d_ws) > ws_size) return;  // workspace too small: fail loudly (poisoned out)

    // 1) casts + zero Z
    prep_kernel<<<8720, 256, 0, stream>>>(xs, Wk, Wq, Wv, Wl, xs_b, Wk_b, Wq_b, Wv_b, Wl_b, Z);

    // 2) fused QKV: z selects weight/bias/output; A (xs_b) shared via strideA=0
    gemm_bt<0,0><<<dim3(128, 4, 3), 256, 0, stream>>>(
        xs_b, Wk_b, bk, bq, bv, (void*)Kb, nullptr, nullptr,
        512, 0L, (long)D_*D_, (long)M_*D_, 0);

    // 3) E = exp(K @ Q^T / 512) per batch; Z column sums via atomics
    gemm_bt<0,1><<<dim3(32, 32, 4), 256, 0, stream>>>(
        Kb, Qb, nullptr, nullptr, nullptr, (void*)E, Z, nullptr,
        S_, (long)S_*D_, (long)S_*D_, (long)S_*S_, S_);

    // 4) invZ
    invz_kernel<<<64, 256, 0, stream>>>(Z, invZ);

    // 5) rowsum
    rowsum_kernel<<<4096, 256, 0, stream>>>(E, invZ, rs);

    // 6) out = tanh((rowsum * V) @ Wl^T + bl)
    gemm_bt<1,2><<<dim3(128, 4, 1), 256, 0, stream>>>(
        Vb, Wl_b, bl, bl, bl, (void*)out, nullptr, rs,
        512, 0L, 0L, 0L, 0);
}